// Round 3
// baseline (162.974 us; speedup 1.0000x reference)
//
#include <hip/hip_runtime.h>
#include <hip/hip_bf16.h>

typedef __bf16 bf16x8 __attribute__((ext_vector_type(8)));
typedef float f32x4 __attribute__((ext_vector_type(4)));
typedef unsigned short u16x8 __attribute__((ext_vector_type(8)));

__device__ __forceinline__ unsigned short f2bf(float f) {
    unsigned int u = __builtin_bit_cast(unsigned int, f);
    unsigned int r = (u + 0x7FFFu + ((u >> 16) & 1u)) >> 16;
    return (unsigned short)r;
}

__device__ __forceinline__ void load_lds_16(const void* g, void* lds) {
    __builtin_amdgcn_global_load_lds(
        (const __attribute__((address_space(1))) unsigned int*)g,
        (__attribute__((address_space(3))) unsigned int*)lds, 16, 0, 0);
}

// ---------- prep v3 (unchanged from R2) ----------
__global__ __launch_bounds__(256) void prep_kernel(
    const float* __restrict__ x, unsigned short* __restrict__ xb,
    const float* __restrict__ W, const float* __restrict__ A,
    const float* __restrict__ B, unsigned short* __restrict__ weffB,
    const float* __restrict__ uh, const float* __restrict__ ih,
    const float* __restrict__ Wu, const float* __restrict__ Wi,
    float* __restrict__ wqu_p, float* __restrict__ wqi_p) {
    __shared__ __align__(16) float Wl[64 * 100];
    __shared__ __align__(16) float Hl[32 * 100];
    const int bx = blockIdx.x;
    const int t = threadIdx.x;
    if (bx < 384) {
        const int g = bx % 24, j = bx / 24;
        const int br = g / 12, ot = g % 12;
        const int bt = j & 1, ks = j >> 1;
        const int o0 = ot * 64, b0 = bt * 32, k0 = ks * 96;
        const float* h = (br ? ih : uh);
        const float* Wm = (br ? Wi : Wu);
        for (int i = t; i < 1536; i += 256) {
            int row = i / 24, c = i % 24;
            *(float4*)&Wl[row * 100 + c * 4] =
                *(const float4*)(Wm + (size_t)(o0 + row) * 768 + k0 + c * 4);
        }
        for (int i = t; i < 768; i += 256) {
            int row = i / 24, c = i % 24;
            *(float4*)&Hl[row * 100 + c * 4] =
                *(const float4*)(h + (size_t)(b0 + row) * 768 + k0 + c * 4);
        }
        __syncthreads();
        const int o2 = t & 31, b4 = t >> 5;
        float acc[2][4] = {};
#pragma unroll 6
        for (int k4 = 0; k4 < 24; ++k4) {
            float4 w0 = *(const float4*)&Wl[o2 * 100 + k4 * 4];
            float4 w1 = *(const float4*)&Wl[(o2 + 32) * 100 + k4 * 4];
#pragma unroll
            for (int jj = 0; jj < 4; ++jj) {
                float4 hb = *(const float4*)&Hl[(b4 * 4 + jj) * 100 + k4 * 4];
                acc[0][jj] += w0.x * hb.x + w0.y * hb.y + w0.z * hb.z + w0.w * hb.w;
                acc[1][jj] += w1.x * hb.x + w1.y * hb.y + w1.z * hb.z + w1.w * hb.w;
            }
        }
        float* part = (br ? wqi_p : wqu_p) + (size_t)ks * 49152;
#pragma unroll
        for (int oo = 0; oo < 2; ++oo)
#pragma unroll
            for (int jj = 0; jj < 4; ++jj)
                part[(size_t)(b0 + b4 * 4 + jj) * 768 + o0 + o2 + oo * 32] = acc[oo][jj];
    } else if (bx < 2688) {
        int idx = bx - 384;
        int o = idx / 3;
        int k = (idx % 3) * 256 + t;
        float acc = W[o * 768 + k];
#pragma unroll
        for (int r = 0; r < 8; ++r) acc += 2.0f * B[o * 8 + r] * A[r * 768 + k];
        weffB[o * 768 + k] = f2bf(acc);
    } else {
        int b2 = bx - 2688;
        const float4* xp = (const float4*)x;
        float4 a[4], c[4];
        int i0 = b2 * 1024 + t;
#pragma unroll
        for (int u = 0; u < 4; ++u) {
            int i = i0 + u * 256;
            a[u] = xp[i * 2];
            c[u] = xp[i * 2 + 1];
        }
#pragma unroll
        for (int u = 0; u < 4; ++u) {
            int i = i0 + u * 256;
            u16x8 r;
            r[0] = f2bf(a[u].x); r[1] = f2bf(a[u].y); r[2] = f2bf(a[u].z); r[3] = f2bf(a[u].w);
            r[4] = f2bf(c[u].x); r[5] = f2bf(c[u].y); r[6] = f2bf(c[u].z); r[7] = f2bf(c[u].w);
            *(u16x8*)(xb + (size_t)i * 8) = r;
        }
    }
}

// ---------- fused GEMM v4: single-As + double-Bs, build/DMA overlapped with MFMA ----------
__global__ __launch_bounds__(256, 3) void gemm_fused_kernel(
    const unsigned short* __restrict__ Xb, const unsigned short* __restrict__ WeffB,
    const float* __restrict__ VU, const float* __restrict__ VI,
    const float* __restrict__ wqu_p, const float* __restrict__ wqi_p,
    const float* __restrict__ bias, float* __restrict__ out) {
    __shared__ __align__(16) unsigned short As[128 * 64];       // 16 KB
    __shared__ __align__(16) unsigned short Bs[2][128 * 64];    // 32 KB (double-buffered)
    __shared__ __align__(16) unsigned int vui[32 * 26];
    __shared__ __align__(16) float wqs[32 * 8];
    __shared__ float bias_s[128];
    const int tid = threadIdx.x;
    const int wave = tid >> 6, lane = tid & 63;
    const int id = blockIdx.x;
    const int nt = id >> 7, rem = id & 127, b = rem >> 1, mt = rem & 1;
    const int s0 = mt * 128, n0 = nt * 128;

    // ---- one-time staging ----
    for (int i = tid; i < 768; i += 256) {
        int n = i >> 5, m = i & 31;
        vui[m * 26 + n] = ((unsigned int)f2bf(VU[i]) << 16) | (unsigned int)f2bf(VI[i]);
    }
    {
        int q = tid >> 3, g = (tid >> 1) & 3, brs = tid & 1;
        const float* p = (brs ? wqi_p : wqu_p) + b * 768 + q * 24 + nt * 4 + g;
        float s = 0.0f;
#pragma unroll
        for (int ks = 0; ks < 8; ++ks) s += p[(size_t)ks * 49152];
        wqs[tid] = s;
    }
    if (tid < 128) bias_s[tid] = bias[n0 + tid];
    __syncthreads();

    const unsigned short* Abase = Xb + (size_t)(b * 256 + s0) * 768;
    const unsigned short* Bbase = WeffB + (size_t)n0 * 768;
    const int wm = wave & 1, wn = wave >> 1;
    const int lrow = lane >> 3, lcp = lane & 7;
    const int rg = tid >> 3, cc = tid & 7;
    const int sl = cc ^ (rg & 7);
    const unsigned short* Wp0 = Bbase + (size_t)rg * 768 + cc * 8;

    u16x8 wreg[4];

    // B-build: values for K-tile starting at kkb, from wreg, into bs_w
    auto build = [&](int kkb, unsigned short* bs_w) {
        int kb = kkb + cc * 8;
        int q = (kb * 2731) >> 16;
        int n0c = kb - q * 24;
        const unsigned int* vp = &vui[rg * 26 + n0c];
        uint2 pv01 = *(const uint2*)(vp);
        uint2 pv23 = *(const uint2*)(vp + 2);
        uint2 pv45 = *(const uint2*)(vp + 4);
        uint2 pv67 = *(const uint2*)(vp + 6);
        unsigned int pv[8] = {pv01.x, pv01.y, pv23.x, pv23.y, pv45.x, pv45.y, pv67.x, pv67.y};
        float fu[8], fi[8];
#pragma unroll
        for (int j = 0; j < 8; ++j) {
            fu[j] = __builtin_bit_cast(float, pv[j] & 0xFFFF0000u);
            fi[j] = __builtin_bit_cast(float, pv[j] << 16);
        }
        const float4* wp4 = (const float4*)&wqs[q * 8];
        float4 wa = wp4[0], wb = wp4[1];
        float wu[4] = {wa.x, wa.z, wb.x, wb.z};
        float wi[4] = {wa.y, wa.w, wb.y, wb.w};
#pragma unroll
        for (int g = 0; g < 4; ++g) {
            uint4 wd = __builtin_bit_cast(uint4, wreg[g]);
            unsigned int warr[4] = {wd.x, wd.y, wd.z, wd.w};
            unsigned int kvw[4];
#pragma unroll
            for (int p = 0; p < 4; ++p) {
                float lo = __builtin_bit_cast(float, warr[p] << 16);
                float hi = __builtin_bit_cast(float, warr[p] & 0xFFFF0000u);
                float v0 = fmaf(fi[2 * p],     wi[g], fmaf(fu[2 * p],     wu[g], lo));
                float v1 = fmaf(fi[2 * p + 1], wi[g], fmaf(fu[2 * p + 1], wu[g], hi));
                kvw[p] = __builtin_amdgcn_perm(__builtin_bit_cast(unsigned int, v1),
                                               __builtin_bit_cast(unsigned int, v0),
                                               0x07060302u);
            }
            *(uint4*)(bs_w + (g * 32 + rg) * 64 + sl * 8) =
                make_uint4(kvw[0], kvw[1], kvw[2], kvw[3]);
        }
    };

    auto dma_A = [&](int kk) {
#pragma unroll
        for (int u = 0; u < 4; ++u) {
            int tA = wave * 4 + u;
            int r = tA * 8 + lrow;
            int c = lcp ^ (r & 7);
            load_lds_16(Abase + (size_t)r * 768 + kk + c * 8, (void*)(As + tA * 512));
        }
    };

    // ---- prologue: DMA A(0); wreg(0); build(0) -> Bs[0] ----
    dma_A(0);
#pragma unroll
    for (int g = 0; g < 4; ++g) wreg[g] = *(const u16x8*)(Wp0 + (size_t)g * 32 * 768);
    build(0, &Bs[0][0]);

    f32x4 acc[4][4] = {};

    for (int t = 0; t < 12; ++t) {
        const int kk = t * 64;
        __syncthreads();   // barrier_A: As(t) + Bs[t&1] ready (vmcnt drained, covered)
        // hoist ALL A-fragments for this step (both halves)
        bf16x8 af2[2][4];
#pragma unroll
        for (int h = 0; h < 2; ++h) {
            const int cb = h * 4 + (lane >> 4);
            const int rl = lane & 15;
#pragma unroll
            for (int i = 0; i < 4; ++i) {
                int r = wm * 64 + i * 16 + rl;
                int c = cb ^ (r & 7);
                af2[h][i] = *(const bf16x8*)(As + r * 64 + c * 8);
            }
        }
        __syncthreads();   // barrier_B: all As reads complete -> safe to overwrite As
        if (t < 11) {
            dma_A(kk + 64);                     // covered by the MFMA phase below
            const unsigned short* Wn = Wp0 + kk + 64;
#pragma unroll
            for (int g = 0; g < 4; ++g) wreg[g] = *(const u16x8*)(Wn + (size_t)g * 32 * 768);
        }
        const unsigned short* bs_r = &Bs[t & 1][0];
#pragma unroll
        for (int h = 0; h < 2; ++h) {
            const int cb = h * 4 + (lane >> 4);
            const int rl = lane & 15;
            bf16x8 bw[4];
#pragma unroll
            for (int j = 0; j < 4; ++j) {
                int r = wn * 64 + j * 16 + rl;
                int c = cb ^ (r & 7);
                bw[j] = *(const bf16x8*)(bs_r + r * 64 + c * 8);
            }
#pragma unroll
            for (int i = 0; i < 4; ++i)
#pragma unroll
                for (int j = 0; j < 4; ++j)
                    acc[i][j] = __builtin_amdgcn_mfma_f32_16x16x32_bf16(af2[h][i], bw[j], acc[i][j], 0, 0, 0);
        }
        if (t < 11) build(kk + 64, &Bs[(t + 1) & 1][0]);   // overlaps MFMA above
    }

    // epilogue: C/D layout col=lane&15, row=(lane>>4)*4+reg
    const int cl = lane & 15, rq = lane >> 4;
#pragma unroll
    for (int j = 0; j < 4; ++j) {
        int nn = wn * 64 + j * 16 + cl;
        float bv = bias_s[nn];
#pragma unroll
        for (int i = 0; i < 4; ++i) {
            int mrow = s0 + wm * 64 + i * 16 + rq * 4;
            float* op = out + (size_t)(b * 256 + mrow) * 768 + n0 + nn;
#pragma unroll
            for (int g = 0; g < 4; ++g) op[(size_t)g * 768] = acc[i][j][g] + bv;
        }
    }
}

// ---------- fallback path (small ws) ----------
__global__ void weff_kernel(const float* __restrict__ W, const float* __restrict__ A,
                            const float* __restrict__ B, float* __restrict__ Weff) {
    int o = blockIdx.x / 3;
    int k = (blockIdx.x % 3) * 256 + threadIdx.x;
    float acc = W[o * 768 + k];
#pragma unroll
    for (int r = 0; r < 8; ++r) acc += 2.0f * B[o * 8 + r] * A[r * 768 + k];
    Weff[o * 768 + k] = acc;
}

__global__ void wq2_kernel(const float* __restrict__ uh, const float* __restrict__ ih,
                           const float* __restrict__ Wu, const float* __restrict__ Wi,
                           float* __restrict__ wqu, float* __restrict__ wqi) {
    int bx = blockIdx.x;
    int og = bx % 192;
    int rest = bx / 192;
    int b = rest & 63;
    int br = rest >> 6;
    int wave = threadIdx.x >> 6, lane = threadIdx.x & 63;
    int o = og * 4 + wave;
    const float* h = (br ? ih : uh) + b * 768;
    const float* Wrow = (br ? Wi : Wu) + (size_t)o * 768;
    const float4* hp = (const float4*)(h + lane * 12);
    const float4* wp = (const float4*)(Wrow + lane * 12);
    float s = 0.0f;
#pragma unroll
    for (int j = 0; j < 3; ++j) {
        float4 hv = hp[j], wv = wp[j];
        s += hv.x * wv.x + hv.y * wv.y + hv.z * wv.z + hv.w * wv.w;
    }
#pragma unroll
    for (int off = 32; off; off >>= 1) s += __shfl_down(s, off);
    if (lane == 0) (br ? wqi : wqu)[b * 768 + o] = s;
}

__global__ void naive_kernel(const float* __restrict__ x, const float* __restrict__ Weff,
                             const float* __restrict__ wqu, const float* __restrict__ wqi,
                             const float* __restrict__ VU, const float* __restrict__ VI,
                             const float* __restrict__ bias, float* __restrict__ out) {
    int bs_ = blockIdx.x / 3;
    int chunk = blockIdx.x % 3;
    int b = bs_ >> 8;
    __shared__ float xs[768];
    for (int i = threadIdx.x; i < 768; i += 256) xs[i] = x[(size_t)bs_ * 768 + i];
    __syncthreads();
    int o = chunk * 256 + threadIdx.x;
    int m = o & 31, l = o >> 5;
    float acc = bias[o];
    for (int q = 0; q < 32; ++q) {
        float wu = wqu[b * 768 + q * 24 + l];
        float wi = wqi[b * 768 + q * 24 + l];
#pragma unroll
        for (int n = 0; n < 24; ++n) {
            int k = q * 24 + n;
            float w = Weff[o * 768 + k] + VU[n * 32 + m] * wu + VI[n * 32 + m] * wi;
            acc += xs[k] * w;
        }
    }
    out[(size_t)bs_ * 768 + o] = acc;
}

extern "C" void kernel_launch(void* const* d_in, const int* in_sizes, int n_in,
                              void* d_out, int out_size, void* d_ws, size_t ws_size,
                              hipStream_t stream) {
    const float* x  = (const float*)d_in[0];
    const float* uh = (const float*)d_in[1];
    const float* ih = (const float*)d_in[2];
    const float* W  = (const float*)d_in[3];
    const float* bv = (const float*)d_in[4];
    const float* A  = (const float*)d_in[5];
    const float* B  = (const float*)d_in[6];
    const float* Wu = (const float*)d_in[7];
    const float* VU = (const float*)d_in[8];
    const float* Wi = (const float*)d_in[9];
    const float* VI = (const float*)d_in[10];
    float* out = (float*)d_out;

    const size_t off_xb   = 0;                        // 25,165,824 B
    const size_t off_weff = 25165824;                 // 1,179,648 B (bf16)
    const size_t off_wqu  = off_weff + 1179648;       // 8 slabs x 196,608 B
    const size_t off_wqi  = off_wqu + 1572864;
    const size_t need     = off_wqi + 1572864;        // ~29.5 MB

    char* ws = (char*)d_ws;
    if (ws_size >= need) {
        unsigned short* xb    = (unsigned short*)(ws + off_xb);
        unsigned short* weffB = (unsigned short*)(ws + off_weff);
        float* wqu_p = (float*)(ws + off_wqu);
        float* wqi_p = (float*)(ws + off_wqi);
        prep_kernel<<<4224, 256, 0, stream>>>(x, xb, W, A, B, weffB, uh, ih, Wu, Wi, wqu_p, wqi_p);
        gemm_fused_kernel<<<768, 256, 0, stream>>>(xb, weffB, VU, VI, wqu_p, wqi_p, bv, out);
    } else {
        float* weff = (float*)ws;
        float* wqu  = weff + 589824;
        float* wqi  = wqu + 49152;
        weff_kernel<<<2304, 256, 0, stream>>>(W, A, B, weff);
        wq2_kernel<<<24576, 256, 0, stream>>>(uh, ih, Wu, Wi, wqu, wqi);
        naive_kernel<<<49152, 256, 0, stream>>>(x, weff, wqu, wqi, VU, VI, bv, out);
    }
}

// Round 4
// 148.020 us; speedup vs baseline: 1.1010x; 1.1010x over previous
//
#include <hip/hip_runtime.h>
#include <hip/hip_bf16.h>

typedef __bf16 bf16x8 __attribute__((ext_vector_type(8)));
typedef float f32x4 __attribute__((ext_vector_type(4)));
typedef unsigned short u16x8 __attribute__((ext_vector_type(8)));

__device__ __forceinline__ unsigned short f2bf(float f) {
    unsigned int u = __builtin_bit_cast(unsigned int, f);
    unsigned int r = (u + 0x7FFFu + ((u >> 16) & 1u)) >> 16;
    return (unsigned short)r;
}

__device__ __forceinline__ void load_lds_16(const void* g, void* lds) {
    __builtin_amdgcn_global_load_lds(
        (const __attribute__((address_space(1))) unsigned int*)g,
        (__attribute__((address_space(3))) unsigned int*)lds, 16, 0, 0);
}

// ---------- prep v3 (unchanged) ----------
__global__ __launch_bounds__(256) void prep_kernel(
    const float* __restrict__ x, unsigned short* __restrict__ xb,
    const float* __restrict__ W, const float* __restrict__ A,
    const float* __restrict__ B, unsigned short* __restrict__ weffB,
    const float* __restrict__ uh, const float* __restrict__ ih,
    const float* __restrict__ Wu, const float* __restrict__ Wi,
    float* __restrict__ wqu_p, float* __restrict__ wqi_p) {
    __shared__ __align__(16) float Wl[64 * 100];
    __shared__ __align__(16) float Hl[32 * 100];
    const int bx = blockIdx.x;
    const int t = threadIdx.x;
    if (bx < 384) {
        const int g = bx % 24, j = bx / 24;
        const int br = g / 12, ot = g % 12;
        const int bt = j & 1, ks = j >> 1;
        const int o0 = ot * 64, b0 = bt * 32, k0 = ks * 96;
        const float* h = (br ? ih : uh);
        const float* Wm = (br ? Wi : Wu);
        for (int i = t; i < 1536; i += 256) {
            int row = i / 24, c = i % 24;
            *(float4*)&Wl[row * 100 + c * 4] =
                *(const float4*)(Wm + (size_t)(o0 + row) * 768 + k0 + c * 4);
        }
        for (int i = t; i < 768; i += 256) {
            int row = i / 24, c = i % 24;
            *(float4*)&Hl[row * 100 + c * 4] =
                *(const float4*)(h + (size_t)(b0 + row) * 768 + k0 + c * 4);
        }
        __syncthreads();
        const int o2 = t & 31, b4 = t >> 5;
        float acc[2][4] = {};
#pragma unroll 6
        for (int k4 = 0; k4 < 24; ++k4) {
            float4 w0 = *(const float4*)&Wl[o2 * 100 + k4 * 4];
            float4 w1 = *(const float4*)&Wl[(o2 + 32) * 100 + k4 * 4];
#pragma unroll
            for (int jj = 0; jj < 4; ++jj) {
                float4 hb = *(const float4*)&Hl[(b4 * 4 + jj) * 100 + k4 * 4];
                acc[0][jj] += w0.x * hb.x + w0.y * hb.y + w0.z * hb.z + w0.w * hb.w;
                acc[1][jj] += w1.x * hb.x + w1.y * hb.y + w1.z * hb.z + w1.w * hb.w;
            }
        }
        float* part = (br ? wqi_p : wqu_p) + (size_t)ks * 49152;
#pragma unroll
        for (int oo = 0; oo < 2; ++oo)
#pragma unroll
            for (int jj = 0; jj < 4; ++jj)
                part[(size_t)(b0 + b4 * 4 + jj) * 768 + o0 + o2 + oo * 32] = acc[oo][jj];
    } else if (bx < 2688) {
        int idx = bx - 384;
        int o = idx / 3;
        int k = (idx % 3) * 256 + t;
        float acc = W[o * 768 + k];
#pragma unroll
        for (int r = 0; r < 8; ++r) acc += 2.0f * B[o * 8 + r] * A[r * 768 + k];
        weffB[o * 768 + k] = f2bf(acc);
    } else {
        int b2 = bx - 2688;
        const float4* xp = (const float4*)x;
        float4 a[4], c[4];
        int i0 = b2 * 1024 + t;
#pragma unroll
        for (int u = 0; u < 4; ++u) {
            int i = i0 + u * 256;
            a[u] = xp[i * 2];
            c[u] = xp[i * 2 + 1];
        }
#pragma unroll
        for (int u = 0; u < 4; ++u) {
            int i = i0 + u * 256;
            u16x8 r;
            r[0] = f2bf(a[u].x); r[1] = f2bf(a[u].y); r[2] = f2bf(a[u].z); r[3] = f2bf(a[u].w);
            r[4] = f2bf(c[u].x); r[5] = f2bf(c[u].y); r[6] = f2bf(c[u].z); r[7] = f2bf(c[u].w);
            *(u16x8*)(xb + (size_t)i * 8) = r;
        }
    }
}

// ---------- fused GEMM (R2 structure: single As + single Bs, 3 blocks/CU) ----------
// Change vs R2: wreg(t+1) prefetch moved AFTER the first barrier so its L2 latency
// is covered by the frag-read+MFMA phase instead of being drained immediately.
__global__ __launch_bounds__(256, 3) void gemm_fused_kernel(
    const unsigned short* __restrict__ Xb, const unsigned short* __restrict__ WeffB,
    const float* __restrict__ VU, const float* __restrict__ VI,
    const float* __restrict__ wqu_p, const float* __restrict__ wqi_p,
    const float* __restrict__ bias, float* __restrict__ out) {
    __shared__ __align__(16) unsigned short As[128 * 64];
    __shared__ __align__(16) unsigned short Bs[128 * 64];
    __shared__ __align__(16) unsigned int vui[32 * 26]; // [m][n pad26], (bf16(VU)<<16)|bf16(VI)
    __shared__ __align__(16) float wqs[32 * 8];          // [q][g][{u,i}]
    __shared__ float bias_s[128];
    const int tid = threadIdx.x;
    const int wave = tid >> 6, lane = tid & 63;
    const int id = blockIdx.x;            // nt*128 + b*2 + mt (same-A blocks = same XCD)
    const int nt = id >> 7, rem = id & 127, b = rem >> 1, mt = rem & 1;
    const int s0 = mt * 128, n0 = nt * 128;

    // ---- one-time staging ----
    for (int i = tid; i < 768; i += 256) {
        int n = i >> 5, m = i & 31;
        vui[m * 26 + n] = ((unsigned int)f2bf(VU[i]) << 16) | (unsigned int)f2bf(VI[i]);
    }
    {
        int q = tid >> 3, g = (tid >> 1) & 3, brs = tid & 1;
        const float* p = (brs ? wqi_p : wqu_p) + b * 768 + q * 24 + nt * 4 + g;
        float s = 0.0f;
#pragma unroll
        for (int ks = 0; ks < 8; ++ks) s += p[(size_t)ks * 49152];
        wqs[tid] = s;
    }
    if (tid < 128) bias_s[tid] = bias[n0 + tid];
    __syncthreads();

    const unsigned short* Abase = Xb + (size_t)(b * 256 + s0) * 768;
    const unsigned short* Bbase = WeffB + (size_t)n0 * 768;
    const int wm = wave & 1, wn = wave >> 1;
    const int lrow = lane >> 3, lcp = lane & 7;      // A-DMA mapping
    const int rg = tid >> 3, cc = tid & 7;           // B-build: rows g*32+rg, chunk cc
    const int sl = cc ^ (rg & 7);                    // physical slot (same all g)
    const unsigned short* Wp0 = Bbase + (size_t)rg * 768 + cc * 8;

    f32x4 acc[4][4] = {};
    u16x8 wreg[4];
#pragma unroll
    for (int g = 0; g < 4; ++g) wreg[g] = *(const u16x8*)(Wp0 + (size_t)g * 32 * 768);

    for (int kk = 0; kk < 768; kk += 64) {
        // async DMA staging of As
#pragma unroll
        for (int u = 0; u < 4; ++u) {
            int tA = wave * 4 + u;
            int r = tA * 8 + lrow;
            int c = lcp ^ (r & 7);
            load_lds_16(Abase + (size_t)r * 768 + kk + c * 8, (void*)(As + tA * 512));
        }
        // K values for chunk cc: k = kb..kb+7, constant q, no n-wrap
        {
            int kb = kk + cc * 8;
            int q = (kb * 2731) >> 16;
            int n0c = kb - q * 24;                   // 0, 8, or 16
            const unsigned int* vp = &vui[rg * 26 + n0c];
            uint2 pv01 = *(const uint2*)(vp);
            uint2 pv23 = *(const uint2*)(vp + 2);
            uint2 pv45 = *(const uint2*)(vp + 4);
            uint2 pv67 = *(const uint2*)(vp + 6);
            unsigned int pv[8] = {pv01.x, pv01.y, pv23.x, pv23.y, pv45.x, pv45.y, pv67.x, pv67.y};
            float fu[8], fi[8];
#pragma unroll
            for (int j = 0; j < 8; ++j) {
                fu[j] = __builtin_bit_cast(float, pv[j] & 0xFFFF0000u);
                fi[j] = __builtin_bit_cast(float, pv[j] << 16);
            }
            const float4* wp4 = (const float4*)&wqs[q * 8];
            float4 wa = wp4[0], wb = wp4[1];         // {u0,i0,u1,i1},{u2,i2,u3,i3}
            float wu[4] = {wa.x, wa.z, wb.x, wb.z};
            float wi[4] = {wa.y, wa.w, wb.y, wb.w};
#pragma unroll
            for (int g = 0; g < 4; ++g) {
                uint4 wd = __builtin_bit_cast(uint4, wreg[g]);
                unsigned int warr[4] = {wd.x, wd.y, wd.z, wd.w};
                unsigned int kvw[4];
#pragma unroll
                for (int p = 0; p < 4; ++p) {
                    float lo = __builtin_bit_cast(float, warr[p] << 16);
                    float hi = __builtin_bit_cast(float, warr[p] & 0xFFFF0000u);
                    float v0 = fmaf(fi[2 * p],     wi[g], fmaf(fu[2 * p],     wu[g], lo));
                    float v1 = fmaf(fi[2 * p + 1], wi[g], fmaf(fu[2 * p + 1], wu[g], hi));
                    kvw[p] = __builtin_amdgcn_perm(__builtin_bit_cast(unsigned int, v1),
                                                   __builtin_bit_cast(unsigned int, v0),
                                                   0x07060302u);
                }
                *(uint4*)(Bs + (g * 32 + rg) * 64 + sl * 8) =
                    make_uint4(kvw[0], kvw[1], kvw[2], kvw[3]);
            }
        }
        __syncthreads();
        // register prefetch of next Weff chunk — now covered by the MFMA phase,
        // drains at the trailing barrier instead of immediately.
        if (kk < 704) {
            const unsigned short* Wn = Wp0 + kk + 64;
#pragma unroll
            for (int g = 0; g < 4; ++g) wreg[g] = *(const u16x8*)(Wn + (size_t)g * 32 * 768);
        }
#pragma unroll
        for (int h = 0; h < 2; ++h) {
            const int cb = h * 4 + (lane >> 4);
            const int rl = lane & 15;
            bf16x8 af[4], bw[4];
#pragma unroll
            for (int i = 0; i < 4; ++i) {
                int r = wm * 64 + i * 16 + rl;
                int c = cb ^ (r & 7);
                af[i] = *(const bf16x8*)(As + r * 64 + c * 8);
            }
#pragma unroll
            for (int j = 0; j < 4; ++j) {
                int r = wn * 64 + j * 16 + rl;
                int c = cb ^ (r & 7);
                bw[j] = *(const bf16x8*)(Bs + r * 64 + c * 8);
            }
#pragma unroll
            for (int i = 0; i < 4; ++i)
#pragma unroll
                for (int j = 0; j < 4; ++j)
                    acc[i][j] = __builtin_amdgcn_mfma_f32_16x16x32_bf16(af[i], bw[j], acc[i][j], 0, 0, 0);
        }
        __syncthreads();
    }

    // epilogue: C/D layout col=lane&15, row=(lane>>4)*4+reg
    const int cl = lane & 15, rq = lane >> 4;
#pragma unroll
    for (int j = 0; j < 4; ++j) {
        int nn = wn * 64 + j * 16 + cl;
        float bv = bias_s[nn];
#pragma unroll
        for (int i = 0; i < 4; ++i) {
            int mrow = s0 + wm * 64 + i * 16 + rq * 4;
            float* op = out + (size_t)(b * 256 + mrow) * 768 + n0 + nn;
#pragma unroll
            for (int g = 0; g < 4; ++g) op[(size_t)g * 768] = acc[i][j][g] + bv;
        }
    }
}

// ---------- fallback path (small ws) ----------
__global__ void weff_kernel(const float* __restrict__ W, const float* __restrict__ A,
                            const float* __restrict__ B, float* __restrict__ Weff) {
    int o = blockIdx.x / 3;
    int k = (blockIdx.x % 3) * 256 + threadIdx.x;
    float acc = W[o * 768 + k];
#pragma unroll
    for (int r = 0; r < 8; ++r) acc += 2.0f * B[o * 8 + r] * A[r * 768 + k];
    Weff[o * 768 + k] = acc;
}

__global__ void wq2_kernel(const float* __restrict__ uh, const float* __restrict__ ih,
                           const float* __restrict__ Wu, const float* __restrict__ Wi,
                           float* __restrict__ wqu, float* __restrict__ wqi) {
    int bx = blockIdx.x;
    int og = bx % 192;
    int rest = bx / 192;
    int b = rest & 63;
    int br = rest >> 6;
    int wave = threadIdx.x >> 6, lane = threadIdx.x & 63;
    int o = og * 4 + wave;
    const float* h = (br ? ih : uh) + b * 768;
    const float* Wrow = (br ? Wi : Wu) + (size_t)o * 768;
    const float4* hp = (const float4*)(h + lane * 12);
    const float4* wp = (const float4*)(Wrow + lane * 12);
    float s = 0.0f;
#pragma unroll
    for (int j = 0; j < 3; ++j) {
        float4 hv = hp[j], wv = wp[j];
        s += hv.x * wv.x + hv.y * wv.y + hv.z * wv.z + hv.w * wv.w;
    }
#pragma unroll
    for (int off = 32; off; off >>= 1) s += __shfl_down(s, off);
    if (lane == 0) (br ? wqi : wqu)[b * 768 + o] = s;
}

__global__ void naive_kernel(const float* __restrict__ x, const float* __restrict__ Weff,
                             const float* __restrict__ wqu, const float* __restrict__ wqi,
                             const float* __restrict__ VU, const float* __restrict__ VI,
                             const float* __restrict__ bias, float* __restrict__ out) {
    int bs_ = blockIdx.x / 3;
    int chunk = blockIdx.x % 3;
    int b = bs_ >> 8;
    __shared__ float xs[768];
    for (int i = threadIdx.x; i < 768; i += 256) xs[i] = x[(size_t)bs_ * 768 + i];
    __syncthreads();
    int o = chunk * 256 + threadIdx.x;
    int m = o & 31, l = o >> 5;
    float acc = bias[o];
    for (int q = 0; q < 32; ++q) {
        float wu = wqu[b * 768 + q * 24 + l];
        float wi = wqi[b * 768 + q * 24 + l];
#pragma unroll
        for (int n = 0; n < 24; ++n) {
            int k = q * 24 + n;
            float w = Weff[o * 768 + k] + VU[n * 32 + m] * wu + VI[n * 32 + m] * wi;
            acc += xs[k] * w;
        }
    }
    out[(size_t)bs_ * 768 + o] = acc;
}

extern "C" void kernel_launch(void* const* d_in, const int* in_sizes, int n_in,
                              void* d_out, int out_size, void* d_ws, size_t ws_size,
                              hipStream_t stream) {
    const float* x  = (const float*)d_in[0];
    const float* uh = (const float*)d_in[1];
    const float* ih = (const float*)d_in[2];
    const float* W  = (const float*)d_in[3];
    const float* bv = (const float*)d_in[4];
    const float* A  = (const float*)d_in[5];
    const float* B  = (const float*)d_in[6];
    const float* Wu = (const float*)d_in[7];
    const float* VU = (const float*)d_in[8];
    const float* Wi = (const float*)d_in[9];
    const float* VI = (const float*)d_in[10];
    float* out = (float*)d_out;

    const size_t off_xb   = 0;                        // 25,165,824 B
    const size_t off_weff = 25165824;                 // 1,179,648 B (bf16)
    const size_t off_wqu  = off_weff + 1179648;       // 8 slabs x 196,608 B
    const size_t off_wqi  = off_wqu + 1572864;
    const size_t need     = off_wqi + 1572864;        // ~29.5 MB

    char* ws = (char*)d_ws;
    if (ws_size >= need) {
        unsigned short* xb    = (unsigned short*)(ws + off_xb);
        unsigned short* weffB = (unsigned short*)(ws + off_weff);
        float* wqu_p = (float*)(ws + off_wqu);
        float* wqi_p = (float*)(ws + off_wqi);
        prep_kernel<<<4224, 256, 0, stream>>>(x, xb, W, A, B, weffB, uh, ih, Wu, Wi, wqu_p, wqi_p);
        gemm_fused_kernel<<<768, 256, 0, stream>>>(xb, weffB, VU, VI, wqu_p, wqi_p, bv, out);
    } else {
        float* weff = (float*)ws;
        float* wqu  = weff + 589824;
        float* wqi  = wqu + 49152;
        weff_kernel<<<2304, 256, 0, stream>>>(W, A, B, weff);
        wq2_kernel<<<24576, 256, 0, stream>>>(uh, ih, Wu, Wi, wqu, wqi);
        naive_kernel<<<49152, 256, 0, stream>>>(x, weff, wqu, wqi, VU, VI, bv, out);
    }
}